// Round 13
// baseline (256.655 us; speedup 1.0000x reference)
//
#include <hip/hip_runtime.h>

#define NG 128
#define G3 (NG*NG*NG)
#define SCAN_NB 256            // coarse scan blocks
#define SCAN_ITEMS 32          // elements per thread
#define SCAN_CHUNK (256*SCAN_ITEMS)   // 8192 per block; 256 blocks exactly cover G3

__device__ __constant__ const float c_DX      = 1.0f/128.0f;
__device__ __constant__ const float c_INV_DX  = 128.0f;

#define DT      1e-4f
#define P_VOL   ((1.0f/256.0f)*(1.0f/256.0f))
#define P_MASS  P_VOL
#define MU0     (5000.0f/(2.0f*1.2f))
#define LAM0    (5000.0f*0.2f/(1.2f*0.6f))

// 64-byte packed particle record, stored in cell-bucket order
// r0 = {A0, A1, A2, particle_id}   A = x*INV_DX (absolute grid coord; exact)
// r1 = {aff0..3}, r2 = {aff4..7}, r3 = {aff8, mv0, mv1, mv2}
struct __align__(16) PRec {
    float4 r0, r1, r2, r3;
};

// ---------------- 3x3 SVD via Jacobi on A^T A ----------------
// all array indices compile-time (template<P,Q> rotations + register
// compare-swap sort) -> zero scratch
template<int P, int Q>
__device__ inline void jacobi_rot(float S[3][3], float V[3][3]) {
    float apq = S[P][Q];
    if (fabsf(apq) < 1e-24f) return;
    float tau = (S[Q][Q] - S[P][P]) / (2.0f * apq);
    float t = copysignf(1.0f, tau) / (fabsf(tau) + sqrtf(1.0f + tau*tau));
    float c = rsqrtf(1.0f + t*t);
    float sn = t * c;
    #pragma unroll
    for (int k = 0; k < 3; ++k) {
        float Spk = S[P][k], Sqk = S[Q][k];
        S[P][k] = c*Spk - sn*Sqk;
        S[Q][k] = sn*Spk + c*Sqk;
    }
    #pragma unroll
    for (int k = 0; k < 3; ++k) {
        float Skp = S[k][P], Skq = S[k][Q];
        S[k][P] = c*Skp - sn*Skq;
        S[k][Q] = sn*Skp + c*Skq;
    }
    #pragma unroll
    for (int k = 0; k < 3; ++k) {
        float Vkp = V[k][P], Vkq = V[k][Q];
        V[k][P] = c*Vkp - sn*Vkq;
        V[k][Q] = sn*Vkp + c*Vkq;
    }
}

// branchless register swap (keeps everything in VGPRs)
#define CSWAPF(cond, x, y) { float _t = (x); (x) = (cond) ? (y) : (x); (y) = (cond) ? _t : (y); }

__device__ inline void svd3(const float A[9], float U[9], float sv[3], float V[9]) {
    float S[3][3];
    #pragma unroll
    for (int i = 0; i < 3; ++i)
        #pragma unroll
        for (int j = 0; j < 3; ++j) {
            float acc = 0.f;
            #pragma unroll
            for (int k = 0; k < 3; ++k) acc += A[k*3+i]*A[k*3+j];
            S[i][j] = acc;
        }
    float Vm[3][3] = {{1.f,0.f,0.f},{0.f,1.f,0.f},{0.f,0.f,1.f}};
    #pragma unroll
    for (int sweep = 0; sweep < 4; ++sweep) {
        jacobi_rot<0,1>(S, Vm);
        jacobi_rot<0,2>(S, Vm);
        jacobi_rot<1,2>(S, Vm);
    }
    // eigenvalues + eigenvector columns into named registers
    float l0 = S[0][0], l1 = S[1][1], l2 = S[2][2];
    float a0 = Vm[0][0], b0 = Vm[1][0], c0 = Vm[2][0];
    float a1 = Vm[0][1], b1 = Vm[1][1], c1 = Vm[2][1];
    float a2 = Vm[0][2], b2 = Vm[1][2], c2 = Vm[2][2];
    // descending sort; identical comparison network to the original index sort
    bool s01 = l0 < l1;
    CSWAPF(s01, l0, l1) CSWAPF(s01, a0, a1) CSWAPF(s01, b0, b1) CSWAPF(s01, c0, c1)
    bool s02 = l0 < l2;
    CSWAPF(s02, l0, l2) CSWAPF(s02, a0, a2) CSWAPF(s02, b0, b2) CSWAPF(s02, c0, c2)
    bool s12 = l1 < l2;
    CSWAPF(s12, l1, l2) CSWAPF(s12, a1, a2) CSWAPF(s12, b1, b2) CSWAPF(s12, c1, c2)

    // column 0
    {
        float l = fmaxf(l0, 0.f); float sval = sqrtf(l); sv[0] = sval;
        V[0] = a0; V[3] = b0; V[6] = c0;
        float inv = (sval > 1e-12f) ? 1.0f/sval : 0.f;
        U[0] = (A[0]*a0 + A[1]*b0 + A[2]*c0)*inv;
        U[3] = (A[3]*a0 + A[4]*b0 + A[5]*c0)*inv;
        U[6] = (A[6]*a0 + A[7]*b0 + A[8]*c0)*inv;
    }
    // column 1
    {
        float l = fmaxf(l1, 0.f); float sval = sqrtf(l); sv[1] = sval;
        V[1] = a1; V[4] = b1; V[7] = c1;
        float inv = (sval > 1e-12f) ? 1.0f/sval : 0.f;
        U[1] = (A[0]*a1 + A[1]*b1 + A[2]*c1)*inv;
        U[4] = (A[3]*a1 + A[4]*b1 + A[5]*c1)*inv;
        U[7] = (A[6]*a1 + A[7]*b1 + A[8]*c1)*inv;
    }
    // column 2
    {
        float l = fmaxf(l2, 0.f); float sval = sqrtf(l); sv[2] = sval;
        V[2] = a2; V[5] = b2; V[8] = c2;
        float inv = (sval > 1e-12f) ? 1.0f/sval : 0.f;
        U[2] = (A[0]*a2 + A[1]*b2 + A[2]*c2)*inv;
        U[5] = (A[3]*a2 + A[4]*b2 + A[5]*c2)*inv;
        U[8] = (A[6]*a2 + A[7]*b2 + A[8]*c2)*inv;
    }
}

// ---------------- binning helpers ----------------
// from absolute grid coord A: base cell + frac (all fp-exact)
__device__ inline void base_from_A(float A0, float A1, float A2,
                                   int& bi, int& bj, int& bk,
                                   float& fx0, float& fx1, float& fx2) {
    float bxf = floorf(A0 - 0.5f);
    float byf = floorf(A1 - 0.5f);
    float bzf = floorf(A2 - 0.5f);
    bi = (int)bxf; bj = (int)byf; bk = (int)bzf;
    bi = min(max(bi, 0), NG-3); bj = min(max(bj, 0), NG-3); bk = min(max(bk, 0), NG-3);
    fx0 = A0 - bxf;
    fx1 = A1 - byf;
    fx2 = A2 - bzf;
}

// count + per-particle rank within its cell (atomicAdd's return value)
__global__ void __launch_bounds__(256)
count_kernel(const float* __restrict__ x, int* __restrict__ cell_count,
             int* __restrict__ rank, int N) {
    int n = blockIdx.x*256 + threadIdx.x;
    if (n >= N) return;
    int bi, bj, bk; float f0, f1, f2;
    base_from_A(x[3*n+0]*c_INV_DX, x[3*n+1]*c_INV_DX, x[3*n+2]*c_INV_DX,
                bi, bj, bk, f0, f1, f2);
    rank[n] = atomicAdd(&cell_count[(bi*NG + bj)*NG + bk], 1);
}

// ---- single-pass exclusive scan: COARSE decoupled lookback (round-12) -----
// 256 coarse blocks x 8192 elems, wave-parallel lookback. Measured: drops
// out of top-5 (<10us) vs 3-kernel version's ~20us+bubble. Offsets
// bit-identical (integer scan).
__global__ void __launch_bounds__(256)
scan_lookback_kernel(const int* __restrict__ count, int* __restrict__ offset,
                     unsigned long long* __restrict__ state,
                     int* __restrict__ ticket) {
    __shared__ int part[256];
    __shared__ int sh_bid;
    __shared__ int sh_prefix;
    int t = threadIdx.x;
    if (t == 0) sh_bid = atomicAdd(ticket, 1);   // ticket order: preds resident
    __syncthreads();
    int bid = sh_bid;
    size_t base = (size_t)bid*SCAN_CHUNK + (size_t)t*SCAN_ITEMS;

    // thread-local serial scan of 32 contiguous counts
    int local[SCAN_ITEMS];
    int s = 0;
    #pragma unroll
    for (int i = 0; i < SCAN_ITEMS; ++i) { local[i] = s; s += count[base + i]; }

    // block scan over the 256 thread-sums (same Hillis-Steele network)
    part[t] = s;
    __syncthreads();
    for (int off = 1; off < 256; off <<= 1) {
        int v = (t >= off) ? part[t-off] : 0;
        __syncthreads();
        part[t] += v;
        __syncthreads();
    }
    int incl = part[t];
    int aggregate = part[255];
    int excl_thread = incl - s;

    if (t == 0) atomicExch(&state[bid], (1ULL << 32) | (unsigned int)aggregate);

    // wave-parallel lookback (wave 0 only)
    if (t < 64) {
        int prefix = 0;
        int prev = bid - 1;
        while (prev >= 0) {
            int q = prev - t;
            bool need = (q >= 0);
            unsigned long long st;
            do {
                st = need ? atomicAdd(&state[q], 0ULL) : (2ULL << 32);
            } while (need && (st >> 32) == 0ULL);
            bool f2 = ((st >> 32) == 2ULL);
            unsigned long long mask = __ballot(f2);
            int dstar = (mask != 0ULL) ? (__ffsll((unsigned long long)mask) - 1) : 64;
            int contrib = (t <= dstar) ? (int)(st & 0xffffffffULL) : 0;
            #pragma unroll
            for (int off = 1; off < 64; off <<= 1) contrib += __shfl_xor(contrib, off);
            prefix += contrib;
            if (mask != 0ULL) break;   // hit a flag=2 (or q<0 sentinel): done
            prev -= 64;
        }
        if (t == 0) {
            atomicExch(&state[bid], (2ULL << 32) | (unsigned int)(prefix + aggregate));
            sh_prefix = prefix;
        }
    }
    __syncthreads();

    int b0 = sh_prefix + excl_thread;
    #pragma unroll
    for (int i = 0; i < SCAN_ITEMS; ++i) offset[base + i] = b0 + local[i];
    if (bid == SCAN_NB-1 && t == 255) offset[G3] = b0 + s;
}

// ---------------- pre-pass: all per-particle math, coalesced reads ----------------
__global__ void __launch_bounds__(256)
pre_kernel(const float* __restrict__ x, const float* __restrict__ v,
           const float* __restrict__ Cin, const float* __restrict__ Fin,
           const float* __restrict__ Jp_in, const int* __restrict__ material,
           const int* __restrict__ offset, const int* __restrict__ rank,
           PRec* __restrict__ rec, float* __restrict__ out, int N) {
    int n = blockIdx.x*256 + threadIdx.x;
    if (n >= N) return;

    float A0 = x[3*n+0]*c_INV_DX, A1 = x[3*n+1]*c_INV_DX, A2 = x[3*n+2]*c_INV_DX;
    int bi, bj, bk; float f0, f1, f2;
    base_from_A(A0, A1, A2, bi, bj, bk, f0, f1, f2);

    float Cm[9], Fm[9];
    #pragma unroll
    for (int i = 0; i < 9; ++i) { Cm[i] = Cin[9*n+i]; Fm[i] = Fin[9*n+i]; }

    // Fn = (I + DT*C) @ F
    float Fn[9];
    #pragma unroll
    for (int i = 0; i < 3; ++i)
        #pragma unroll
        for (int k = 0; k < 3; ++k) {
            float acc = Fm[i*3+k];
            #pragma unroll
            for (int j = 0; j < 3; ++j) acc += DT * Cm[i*3+j] * Fm[j*3+k];
            Fn[i*3+k] = acc;
        }

    float Jp = Jp_in[n];
    int mat = material[n];
    float h = expf(10.0f*(1.0f - Jp));
    h = fminf(fmaxf(h, 0.1f), 5.0f);
    if (mat == 1) h = 0.3f;
    float mu = (mat == 0) ? 0.0f : MU0*h;
    float la = LAM0*h;

    float U[9], V[9], sv[3];
    svd3(Fn, U, sv, V);

    float J = 1.0f;
    float sig[3];
    #pragma unroll
    for (int d = 0; d < 2; ++d) {
        float s = sv[d];
        float ns = (mat == 2) ? fminf(fmaxf(s, 1.0f-0.025f), 1.0f+0.0045f) : s;
        Jp = Jp * s / ns;
        sig[d] = ns;
        J *= ns;
    }
    sig[2] = sv[2];

    if (mat == 0) {
        float sj = sqrtf(J);
        Fn[0]=sj; Fn[1]=0; Fn[2]=0; Fn[3]=0; Fn[4]=sj; Fn[5]=0; Fn[6]=0; Fn[7]=0; Fn[8]=sj;
    } else if (mat == 2) {
        #pragma unroll
        for (int i = 0; i < 3; ++i)
            #pragma unroll
            for (int k = 0; k < 3; ++k) {
                float acc = 0.f;
                #pragma unroll
                for (int j = 0; j < 3; ++j) acc += U[i*3+j]*sig[j]*V[k*3+j];
                Fn[i*3+k] = acc;
            }
    }

    float R[9];
    #pragma unroll
    for (int i = 0; i < 3; ++i)
        #pragma unroll
        for (int k = 0; k < 3; ++k) {
            float acc = 0.f;
            #pragma unroll
            for (int j = 0; j < 3; ++j) acc += U[i*3+j]*V[k*3+j];
            R[i*3+k] = acc;
        }

    float press = la * J * (J - 1.0f);
    float scale = -DT * P_VOL * 4.0f * c_INV_DX * c_INV_DX;
    float aff[9];
    #pragma unroll
    for (int i = 0; i < 3; ++i)
        #pragma unroll
        for (int k = 0; k < 3; ++k) {
            float acc = 0.f;
            #pragma unroll
            for (int j = 0; j < 3; ++j) acc += (Fn[i*3+j]-R[i*3+j])*Fn[k*3+j];
            acc = 2.0f*mu*acc;
            if (i == k) acc += press;
            aff[i*3+k] = scale*acc + P_MASS*Cm[i*3+k];
        }

    float* po = out + (size_t)n*25;
    po[6] = Jp;
    #pragma unroll
    for (int i = 0; i < 9; ++i) po[7+i] = Fn[i];

    // cell-bucket slot (rank captured by count_kernel's atomicAdd)
    int cell = (bi*NG + bj)*NG + bk;
    int pos = offset[cell] + rank[n];

    float4* rp = (float4*)&rec[pos];
    rp[0] = make_float4(A0, A1, A2, __int_as_float(n));
    rp[1] = make_float4(aff[0], aff[1], aff[2], aff[3]);
    rp[2] = make_float4(aff[4], aff[5], aff[6], aff[7]);
    rp[3] = make_float4(aff[8], P_MASS*v[3*n+0], P_MASS*v[3*n+1], P_MASS*v[3*n+2]);
}

// ------- fused P2G-gather + grid update: LANE-PAIR split, NO atomics -----------
// v13: two lanes per quad (parity split of each bucket range). Round-12 data:
//   gather 62.7us, VALUBusy 41%, issue-bound on the wave-max of per-quad
//   particle totals K_q (spatial density variance -> max/mean ~2x). Splitting
//   each quad's stream across a lane pair makes wave time ~ max32(ceil(K/2))
//   ~= 0.5 * max32(K) < 0.5 * max64(K): straggler term roughly halves.
//   Pair lanes take even/odd local indices of each range (disjoint, ordered);
//   combine via 16 __shfl_xor(.,1) adds (pair lanes share ranges -> identical
//   'any' -> both active). Parity-0 lane writes the 4 cells. Per-cell sum
//   becomes evens+odds -- same reordering class as the (passing) round-1
//   LDS-atomic version; IEEE a+b commutative so both lanes agree bitwise.
// Tested-and-rejected: 2-wide unroll (r2), SW pipeline (r5), 64-thr blocks
//   (r8), XCD swizzle (r8/r9: -7MB fetch but +imbalance).
__global__ void __launch_bounds__(128)
grid_gather_kernel(const PRec* __restrict__ rec, const int* __restrict__ offset,
                   float4* __restrict__ grid, const float* __restrict__ gravity,
                   const float* __restrict__ attr_s, const float* __restrict__ attr_p) {
    __shared__ int rS[9*128];
    __shared__ int rE[9*128];
    int tid = threadIdx.x;
    int par = tid & 1;
    int qid = (blockIdx.x*128 + tid) >> 1;   // quad index (G3/4 total), 2 lanes/quad
    int zq = qid & 31;
    int gj = (qid >> 5) & (NG-1);
    int gi = qid >> 12;
    int zlo = zq*4;

    int bk0 = max(zlo-2, 0), bk1 = min(zlo+3, NG-3);

    // fetch all 9 column ranges (18 independent loads in flight) -> LDS table
    bool any = false;
    #pragma unroll
    for (int di = 0; di < 3; ++di) {
        int bi = gi - 2 + di;
        bool vi = (bi >= 0) && (bi <= NG-3);
        #pragma unroll
        for (int dj = 0; dj < 3; ++dj) {
            int bj = gj - 2 + dj;
            bool vj = vi && (bj >= 0) && (bj <= NG-3);
            int col = ((vj ? bi : 0)*NG + (vj ? bj : 0))*NG;
            int s = vj ? offset[col + bk0]     : 0;
            int e = vj ? offset[col + bk1 + 1] : 0;
            rS[(di*3+dj)*128 + tid] = s;
            rE[(di*3+dj)*128 + tid] = e;
            if (s < e) any = true;
        }
    }

    // quads with zero visits are never read by g2p (any cell g2p reads has a
    // member particle, and member particles lie in this quad's bucket window).
    // Pair lanes share ranges -> identical 'any' -> pairs exit together.
    if (!any) return;

    float ax[4], ay[4], az[4], mm[4];
    #pragma unroll
    for (int h = 0; h < 4; ++h) { ax[h]=0.f; ay[h]=0.f; az[h]=0.f; mm[h]=0.f; }

    float gif = (float)gi, gjf = (float)gj, z0f = (float)zlo;

    // fused parity-split stream over the 9 ranges (per-lane private advance)
    int ridx = 0;
    int e = rE[tid];
    int p = rS[tid] + par;
    while (p >= e) {
        if (++ridx >= 9) break;
        p = rS[ridx*128 + tid] + par; e = rE[ridx*128 + tid];
    }
    while (ridx < 9) {
        const float4* rp = (const float4*)&rec[p];
        float4 r0 = rp[0];
        float4 r1 = rp[1];
        float4 r2 = rp[2];
        float4 r3 = rp[3];

        // symmetric quadratic B-spline N(u), u = cell - A (fp-exact vs ref)
        float ux = gif - r0.x;
        float aux = fabsf(ux);
        float tx = 1.5f - aux;
        float nx = (aux < 0.5f) ? (0.75f - ux*ux) : (0.5f*tx*tx);
        float uy = gjf - r0.y;
        float auy = fabsf(uy);
        float ty = 1.5f - auy;
        float ny = (auy < 0.5f) ? (0.75f - uy*uy) : (0.5f*ty*ty);
        float wgt = nx*ny;                 // reference: x,y weights only

        float uz0 = z0f - r0.z;
        float dpx = ux*c_DX, dpy = uy*c_DX, dpz0 = uz0*c_DX;
        float cx = r3.y + r1.x*dpx + r1.y*dpy + r1.z*dpz0;
        float cy = r3.z + r1.w*dpx + r2.x*dpy + r2.y*dpz0;
        float cz = r3.w + r2.z*dpx + r2.w*dpy + r3.x*dpz0;
        float ix = r1.z*c_DX, iy = r2.y*c_DX, iz = r3.x*c_DX;

        #pragma unroll
        for (int h = 0; h < 4; ++h) {
            float uz = uz0 + (float)h;
            // membership mask: uz in (-1.5, 1.5]
            float w = (uz > -1.5f && uz <= 1.5f) ? wgt : 0.f;
            ax[h] += w*cx; ay[h] += w*cy; az[h] += w*cz; mm[h] += w*P_MASS;
            cx += ix; cy += iy; cz += iz;
        }

        p += 2;
        while (p >= e) {
            if (++ridx >= 9) break;
            p = rS[ridx*128 + tid] + par; e = rE[ridx*128 + tid];
        }
    }

    // pair-combine: evens + odds (commutative add -> both lanes bit-identical)
    #pragma unroll
    for (int h = 0; h < 4; ++h) {
        ax[h] += __shfl_xor(ax[h], 1);
        ay[h] += __shfl_xor(ay[h], 1);
        az[h] += __shfl_xor(az[h], 1);
        mm[h] += __shfl_xor(mm[h], 1);
    }
    if (par != 0) return;

    float gx = DT*gravity[0]*30.0f, gy = DT*gravity[1]*30.0f, gz = DT*gravity[2]*30.0f;
    float apx = attr_p[0], apy = attr_p[1], apz = attr_p[2];
    float as  = attr_s[0] * DT * 100.0f;

    int gidx = (gi*NG + gj)*NG + zlo;
    #pragma unroll
    for (int h = 0; h < 4; ++h) {
        float m = mm[h];
        int gk = zlo + h;
        float gvx = 0.f, gvy = 0.f, gvz = 0.f;
        if (m > 0.f) {
            float inv = 1.0f/m;
            gvx = ax[h]*inv + gx; gvy = ay[h]*inv + gy; gvz = az[h]*inv + gz;
            float dx_ = apx - c_DX*(float)gi;
            float dy_ = apy - c_DX*(float)gj;
            float dz_ = apz - c_DX*(float)gk;
            float nrm = sqrtf(dx_*dx_ + dy_*dy_ + dz_*dz_);
            float sc = as / (0.01f + nrm);
            gvx += dx_*sc; gvy += dy_*sc; gvz += dz_*sc;
            if (gi < 3      && gvx < 0.f) gvx = 0.f;
            if (gi > NG-3   && gvx > 0.f) gvx = 0.f;
            if (gj < 3      && gvy < 0.f) gvy = 0.f;
            if (gj > NG-3   && gvy > 0.f) gvy = 0.f;
            // z unconstrained (matches reference)
        }
        grid[gidx + h] = make_float4(gvx, gvy, gvz, m);
    }
}

// ---------------- G2P (cell-sorted order, coalesced record reads) ----------------
__global__ void __launch_bounds__(256)
g2p_kernel(const PRec* __restrict__ rec, const float4* __restrict__ grid,
           float* __restrict__ out, int N) {
    int gid = blockIdx.x * 256 + threadIdx.x;
    if (gid >= N) return;

    float4 r0 = rec[gid].r0;
    float A0 = r0.x, A1 = r0.y, A2 = r0.z;
    int n = __float_as_int(r0.w);

    int bi, bj, bk; float fx0, fx1, fx2;
    base_from_A(A0, A1, A2, bi, bj, bk, fx0, fx1, fx2);

    float wx[3], wy[3];
    wx[0] = 0.5f*(1.5f-fx0)*(1.5f-fx0); wx[1] = 0.75f-(fx0-1.f)*(fx0-1.f); wx[2] = 0.5f*(fx0-0.5f)*(fx0-0.5f);
    wy[0] = 0.5f*(1.5f-fx1)*(1.5f-fx1); wy[1] = 0.75f-(fx1-1.f)*(fx1-1.f); wy[2] = 0.5f*(fx1-0.5f)*(fx1-0.5f);

    float nvx = 0.f, nvy = 0.f, nvz = 0.f;
    float nC[9];
    #pragma unroll
    for (int i = 0; i < 9; ++i) nC[i] = 0.f;

    #pragma unroll
    for (int i = 0; i < 3; ++i) {
        float dpx = (float)i - fx0;
        #pragma unroll
        for (int j = 0; j < 3; ++j) {
            float wgt = wx[i]*wy[j];
            float dpy = (float)j - fx1;
            int cell0 = ((bi+i)*NG + (bj+j))*NG + bk;
            #pragma unroll
            for (int k = 0; k < 3; ++k) {
                float dpz = (float)k - fx2;
                float4 gv = grid[cell0 + k];
                float wgx = wgt*gv.x, wgy = wgt*gv.y, wgz = wgt*gv.z;
                nvx += wgx; nvy += wgy; nvz += wgz;
                nC[0] += wgx*dpx; nC[1] += wgx*dpy; nC[2] += wgx*dpz;
                nC[3] += wgy*dpx; nC[4] += wgy*dpy; nC[5] += wgy*dpz;
                nC[6] += wgz*dpx; nC[7] += wgz*dpy; nC[8] += wgz*dpz;
            }
        }
    }

    float* po = out + (size_t)n*25;
    float px = A0*c_DX, py = A1*c_DX, pz = A2*c_DX;   // exact reconstruction
    po[0] = px + DT*nvx;
    po[1] = py + DT*nvy;
    po[2] = pz + DT*nvz;
    po[3] = nvx; po[4] = nvy; po[5] = nvz;
    float s4 = 4.0f*c_INV_DX;
    #pragma unroll
    for (int i = 0; i < 9; ++i) po[16+i] = s4*nC[i];
}

extern "C" void kernel_launch(void* const* d_in, const int* in_sizes, int n_in,
                              void* d_out, int out_size, void* d_ws, size_t ws_size,
                              hipStream_t stream) {
    const float* x        = (const float*)d_in[0];
    const float* v        = (const float*)d_in[1];
    const float* C        = (const float*)d_in[2];
    const float* F        = (const float*)d_in[3];
    const float* Jp       = (const float*)d_in[4];
    const float* gravity  = (const float*)d_in[5];
    const float* attr_s   = (const float*)d_in[6];
    const float* attr_p   = (const float*)d_in[7];
    const int*   material = (const int*)d_in[8];
    float* out = (float*)d_out;
    int N = in_sizes[0] / 3;

    // workspace (zeroed region first):
    //   [cell_count G3][state SCAN_NB][ticket pad] | [offset G3+1][rank N][grid][rec]
    char* ws = (char*)d_ws;
    size_t o = 0;
    int* cell_count = (int*)(ws + o);              o += (size_t)G3*sizeof(int);
    unsigned long long* state = (unsigned long long*)(ws + o);
                                                   o += (size_t)SCAN_NB*sizeof(unsigned long long);
    int* ticket     = (int*)(ws + o);              o += 128;   // padded
    size_t zero_bytes = o;
    int* offset     = (int*)(ws + o);              o += ((size_t)G3+1)*sizeof(int);
    int* rank       = (int*)(ws + o);              o += (size_t)N*sizeof(int);
    o = (o + 127) & ~(size_t)127;
    float4* grid    = (float4*)(ws + o);           o += (size_t)G3*sizeof(float4);
    PRec* rec       = (PRec*)(ws + o);             o += (size_t)N*sizeof(PRec);

    hipMemsetAsync(d_ws, 0, zero_bytes, stream);

    int pblocks = (N + 255) / 256;
    count_kernel<<<pblocks, 256, 0, stream>>>(x, cell_count, rank, N);
    scan_lookback_kernel<<<SCAN_NB, 256, 0, stream>>>(cell_count, offset,
                                                      state, ticket);
    pre_kernel<<<pblocks, 256, 0, stream>>>(x, v, C, F, Jp, material,
                                            offset, rank, rec, out, N);
    grid_gather_kernel<<<G3/256, 128, 0, stream>>>(rec, offset, grid,
                                                   gravity, attr_s, attr_p);
    g2p_kernel<<<pblocks, 256, 0, stream>>>(rec, grid, out, N);
}

// Round 14
// 251.615 us; speedup vs baseline: 1.0200x; 1.0200x over previous
//
#include <hip/hip_runtime.h>

#define NG 128
#define G3 (NG*NG*NG)
#define SCAN_NB 256            // coarse scan blocks
#define SCAN_ITEMS 32          // elements per thread
#define SCAN_CHUNK (256*SCAN_ITEMS)   // 8192 per block; 256 blocks exactly cover G3

__device__ __constant__ const float c_DX      = 1.0f/128.0f;
__device__ __constant__ const float c_INV_DX  = 128.0f;

#define DT      1e-4f
#define P_VOL   ((1.0f/256.0f)*(1.0f/256.0f))
#define P_MASS  P_VOL
#define MU0     (5000.0f/(2.0f*1.2f))
#define LAM0    (5000.0f*0.2f/(1.2f*0.6f))

// 64-byte packed particle record, stored in cell-bucket order
// r0 = {A0, A1, A2, particle_id}   A = x*INV_DX (absolute grid coord; exact)
// r1 = {aff0..3}, r2 = {aff4..7}, r3 = {aff8, mv0, mv1, mv2}
struct __align__(16) PRec {
    float4 r0, r1, r2, r3;
};

// ---------------- 3x3 SVD via Jacobi on A^T A ----------------
// all array indices compile-time (template<P,Q> rotations + register
// compare-swap sort) -> zero scratch
template<int P, int Q>
__device__ inline void jacobi_rot(float S[3][3], float V[3][3]) {
    float apq = S[P][Q];
    if (fabsf(apq) < 1e-24f) return;
    float tau = (S[Q][Q] - S[P][P]) / (2.0f * apq);
    float t = copysignf(1.0f, tau) / (fabsf(tau) + sqrtf(1.0f + tau*tau));
    float c = rsqrtf(1.0f + t*t);
    float sn = t * c;
    #pragma unroll
    for (int k = 0; k < 3; ++k) {
        float Spk = S[P][k], Sqk = S[Q][k];
        S[P][k] = c*Spk - sn*Sqk;
        S[Q][k] = sn*Spk + c*Sqk;
    }
    #pragma unroll
    for (int k = 0; k < 3; ++k) {
        float Skp = S[k][P], Skq = S[k][Q];
        S[k][P] = c*Skp - sn*Skq;
        S[k][Q] = sn*Skp + c*Skq;
    }
    #pragma unroll
    for (int k = 0; k < 3; ++k) {
        float Vkp = V[k][P], Vkq = V[k][Q];
        V[k][P] = c*Vkp - sn*Vkq;
        V[k][Q] = sn*Vkp + c*Vkq;
    }
}

// branchless register swap (keeps everything in VGPRs)
#define CSWAPF(cond, x, y) { float _t = (x); (x) = (cond) ? (y) : (x); (y) = (cond) ? _t : (y); }

__device__ inline void svd3(const float A[9], float U[9], float sv[3], float V[9]) {
    float S[3][3];
    #pragma unroll
    for (int i = 0; i < 3; ++i)
        #pragma unroll
        for (int j = 0; j < 3; ++j) {
            float acc = 0.f;
            #pragma unroll
            for (int k = 0; k < 3; ++k) acc += A[k*3+i]*A[k*3+j];
            S[i][j] = acc;
        }
    float Vm[3][3] = {{1.f,0.f,0.f},{0.f,1.f,0.f},{0.f,0.f,1.f}};
    #pragma unroll
    for (int sweep = 0; sweep < 4; ++sweep) {
        jacobi_rot<0,1>(S, Vm);
        jacobi_rot<0,2>(S, Vm);
        jacobi_rot<1,2>(S, Vm);
    }
    // eigenvalues + eigenvector columns into named registers
    float l0 = S[0][0], l1 = S[1][1], l2 = S[2][2];
    float a0 = Vm[0][0], b0 = Vm[1][0], c0 = Vm[2][0];
    float a1 = Vm[0][1], b1 = Vm[1][1], c1 = Vm[2][1];
    float a2 = Vm[0][2], b2 = Vm[1][2], c2 = Vm[2][2];
    // descending sort; identical comparison network to the original index sort
    bool s01 = l0 < l1;
    CSWAPF(s01, l0, l1) CSWAPF(s01, a0, a1) CSWAPF(s01, b0, b1) CSWAPF(s01, c0, c1)
    bool s02 = l0 < l2;
    CSWAPF(s02, l0, l2) CSWAPF(s02, a0, a2) CSWAPF(s02, b0, b2) CSWAPF(s02, c0, c2)
    bool s12 = l1 < l2;
    CSWAPF(s12, l1, l2) CSWAPF(s12, a1, a2) CSWAPF(s12, b1, b2) CSWAPF(s12, c1, c2)

    // column 0
    {
        float l = fmaxf(l0, 0.f); float sval = sqrtf(l); sv[0] = sval;
        V[0] = a0; V[3] = b0; V[6] = c0;
        float inv = (sval > 1e-12f) ? 1.0f/sval : 0.f;
        U[0] = (A[0]*a0 + A[1]*b0 + A[2]*c0)*inv;
        U[3] = (A[3]*a0 + A[4]*b0 + A[5]*c0)*inv;
        U[6] = (A[6]*a0 + A[7]*b0 + A[8]*c0)*inv;
    }
    // column 1
    {
        float l = fmaxf(l1, 0.f); float sval = sqrtf(l); sv[1] = sval;
        V[1] = a1; V[4] = b1; V[7] = c1;
        float inv = (sval > 1e-12f) ? 1.0f/sval : 0.f;
        U[1] = (A[0]*a1 + A[1]*b1 + A[2]*c1)*inv;
        U[4] = (A[3]*a1 + A[4]*b1 + A[5]*c1)*inv;
        U[7] = (A[6]*a1 + A[7]*b1 + A[8]*c1)*inv;
    }
    // column 2
    {
        float l = fmaxf(l2, 0.f); float sval = sqrtf(l); sv[2] = sval;
        V[2] = a2; V[5] = b2; V[8] = c2;
        float inv = (sval > 1e-12f) ? 1.0f/sval : 0.f;
        U[2] = (A[0]*a2 + A[1]*b2 + A[2]*c2)*inv;
        U[5] = (A[3]*a2 + A[4]*b2 + A[5]*c2)*inv;
        U[8] = (A[6]*a2 + A[7]*b2 + A[8]*c2)*inv;
    }
}

// ---------------- binning helpers ----------------
// from absolute grid coord A: base cell + frac (all fp-exact)
__device__ inline void base_from_A(float A0, float A1, float A2,
                                   int& bi, int& bj, int& bk,
                                   float& fx0, float& fx1, float& fx2) {
    float bxf = floorf(A0 - 0.5f);
    float byf = floorf(A1 - 0.5f);
    float bzf = floorf(A2 - 0.5f);
    bi = (int)bxf; bj = (int)byf; bk = (int)bzf;
    bi = min(max(bi, 0), NG-3); bj = min(max(bj, 0), NG-3); bk = min(max(bk, 0), NG-3);
    fx0 = A0 - bxf;
    fx1 = A1 - byf;
    fx2 = A2 - bzf;
}

// count + per-particle rank within its cell (atomicAdd's return value)
__global__ void __launch_bounds__(256)
count_kernel(const float* __restrict__ x, int* __restrict__ cell_count,
             int* __restrict__ rank, int N) {
    int n = blockIdx.x*256 + threadIdx.x;
    if (n >= N) return;
    int bi, bj, bk; float f0, f1, f2;
    base_from_A(x[3*n+0]*c_INV_DX, x[3*n+1]*c_INV_DX, x[3*n+2]*c_INV_DX,
                bi, bj, bk, f0, f1, f2);
    rank[n] = atomicAdd(&cell_count[(bi*NG + bj)*NG + bk], 1);
}

// ---- single-pass exclusive scan: COARSE decoupled lookback (round-12) -----
// 256 coarse blocks x 8192 elems, wave-parallel lookback. Measured: drops
// out of top-5 (<10us) vs 3-kernel version's ~20us+bubble (round-12 win:
// total 264.7 -> 252.7). Round-11's fine-grained version (8192 blocks,
// single-lane lookback) was 130us -- chain depth is everything. Offsets
// bit-identical (integer scan).
__global__ void __launch_bounds__(256)
scan_lookback_kernel(const int* __restrict__ count, int* __restrict__ offset,
                     unsigned long long* __restrict__ state,
                     int* __restrict__ ticket) {
    __shared__ int part[256];
    __shared__ int sh_bid;
    __shared__ int sh_prefix;
    int t = threadIdx.x;
    if (t == 0) sh_bid = atomicAdd(ticket, 1);   // ticket order: preds resident
    __syncthreads();
    int bid = sh_bid;
    size_t base = (size_t)bid*SCAN_CHUNK + (size_t)t*SCAN_ITEMS;

    // thread-local serial scan of 32 contiguous counts
    int local[SCAN_ITEMS];
    int s = 0;
    #pragma unroll
    for (int i = 0; i < SCAN_ITEMS; ++i) { local[i] = s; s += count[base + i]; }

    // block scan over the 256 thread-sums (same Hillis-Steele network)
    part[t] = s;
    __syncthreads();
    for (int off = 1; off < 256; off <<= 1) {
        int v = (t >= off) ? part[t-off] : 0;
        __syncthreads();
        part[t] += v;
        __syncthreads();
    }
    int incl = part[t];
    int aggregate = part[255];
    int excl_thread = incl - s;

    if (t == 0) atomicExch(&state[bid], (1ULL << 32) | (unsigned int)aggregate);

    // wave-parallel lookback (wave 0 only)
    if (t < 64) {
        int prefix = 0;
        int prev = bid - 1;
        while (prev >= 0) {
            int q = prev - t;
            bool need = (q >= 0);
            unsigned long long st;
            do {
                st = need ? atomicAdd(&state[q], 0ULL) : (2ULL << 32);
            } while (need && (st >> 32) == 0ULL);
            bool f2 = ((st >> 32) == 2ULL);
            unsigned long long mask = __ballot(f2);
            int dstar = (mask != 0ULL) ? (__ffsll((unsigned long long)mask) - 1) : 64;
            int contrib = (t <= dstar) ? (int)(st & 0xffffffffULL) : 0;
            #pragma unroll
            for (int off = 1; off < 64; off <<= 1) contrib += __shfl_xor(contrib, off);
            prefix += contrib;
            if (mask != 0ULL) break;   // hit a flag=2 (or q<0 sentinel): done
            prev -= 64;
        }
        if (t == 0) {
            atomicExch(&state[bid], (2ULL << 32) | (unsigned int)(prefix + aggregate));
            sh_prefix = prefix;
        }
    }
    __syncthreads();

    int b0 = sh_prefix + excl_thread;
    #pragma unroll
    for (int i = 0; i < SCAN_ITEMS; ++i) offset[base + i] = b0 + local[i];
    if (bid == SCAN_NB-1 && t == 255) offset[G3] = b0 + s;
}

// ---------------- pre-pass: all per-particle math, coalesced reads ----------------
__global__ void __launch_bounds__(256)
pre_kernel(const float* __restrict__ x, const float* __restrict__ v,
           const float* __restrict__ Cin, const float* __restrict__ Fin,
           const float* __restrict__ Jp_in, const int* __restrict__ material,
           const int* __restrict__ offset, const int* __restrict__ rank,
           PRec* __restrict__ rec, float* __restrict__ out, int N) {
    int n = blockIdx.x*256 + threadIdx.x;
    if (n >= N) return;

    float A0 = x[3*n+0]*c_INV_DX, A1 = x[3*n+1]*c_INV_DX, A2 = x[3*n+2]*c_INV_DX;
    int bi, bj, bk; float f0, f1, f2;
    base_from_A(A0, A1, A2, bi, bj, bk, f0, f1, f2);

    float Cm[9], Fm[9];
    #pragma unroll
    for (int i = 0; i < 9; ++i) { Cm[i] = Cin[9*n+i]; Fm[i] = Fin[9*n+i]; }

    // Fn = (I + DT*C) @ F
    float Fn[9];
    #pragma unroll
    for (int i = 0; i < 3; ++i)
        #pragma unroll
        for (int k = 0; k < 3; ++k) {
            float acc = Fm[i*3+k];
            #pragma unroll
            for (int j = 0; j < 3; ++j) acc += DT * Cm[i*3+j] * Fm[j*3+k];
            Fn[i*3+k] = acc;
        }

    float Jp = Jp_in[n];
    int mat = material[n];
    float h = expf(10.0f*(1.0f - Jp));
    h = fminf(fmaxf(h, 0.1f), 5.0f);
    if (mat == 1) h = 0.3f;
    float mu = (mat == 0) ? 0.0f : MU0*h;
    float la = LAM0*h;

    float U[9], V[9], sv[3];
    svd3(Fn, U, sv, V);

    float J = 1.0f;
    float sig[3];
    #pragma unroll
    for (int d = 0; d < 2; ++d) {
        float s = sv[d];
        float ns = (mat == 2) ? fminf(fmaxf(s, 1.0f-0.025f), 1.0f+0.0045f) : s;
        Jp = Jp * s / ns;
        sig[d] = ns;
        J *= ns;
    }
    sig[2] = sv[2];

    if (mat == 0) {
        float sj = sqrtf(J);
        Fn[0]=sj; Fn[1]=0; Fn[2]=0; Fn[3]=0; Fn[4]=sj; Fn[5]=0; Fn[6]=0; Fn[7]=0; Fn[8]=sj;
    } else if (mat == 2) {
        #pragma unroll
        for (int i = 0; i < 3; ++i)
            #pragma unroll
            for (int k = 0; k < 3; ++k) {
                float acc = 0.f;
                #pragma unroll
                for (int j = 0; j < 3; ++j) acc += U[i*3+j]*sig[j]*V[k*3+j];
                Fn[i*3+k] = acc;
            }
    }

    float R[9];
    #pragma unroll
    for (int i = 0; i < 3; ++i)
        #pragma unroll
        for (int k = 0; k < 3; ++k) {
            float acc = 0.f;
            #pragma unroll
            for (int j = 0; j < 3; ++j) acc += U[i*3+j]*V[k*3+j];
            R[i*3+k] = acc;
        }

    float press = la * J * (J - 1.0f);
    float scale = -DT * P_VOL * 4.0f * c_INV_DX * c_INV_DX;
    float aff[9];
    #pragma unroll
    for (int i = 0; i < 3; ++i)
        #pragma unroll
        for (int k = 0; k < 3; ++k) {
            float acc = 0.f;
            #pragma unroll
            for (int j = 0; j < 3; ++j) acc += (Fn[i*3+j]-R[i*3+j])*Fn[k*3+j];
            acc = 2.0f*mu*acc;
            if (i == k) acc += press;
            aff[i*3+k] = scale*acc + P_MASS*Cm[i*3+k];
        }

    float* po = out + (size_t)n*25;
    po[6] = Jp;
    #pragma unroll
    for (int i = 0; i < 9; ++i) po[7+i] = Fn[i];

    // cell-bucket slot (rank captured by count_kernel's atomicAdd)
    int cell = (bi*NG + bj)*NG + bk;
    int pos = offset[cell] + rank[n];

    float4* rp = (float4*)&rec[pos];
    rp[0] = make_float4(A0, A1, A2, __int_as_float(n));
    rp[1] = make_float4(aff[0], aff[1], aff[2], aff[3]);
    rp[2] = make_float4(aff[4], aff[5], aff[6], aff[7]);
    rp[3] = make_float4(aff[8], P_MASS*v[3*n+0], P_MASS*v[3*n+1], P_MASS*v[3*n+2]);
}

// ------- fused P2G-gather + grid update: one thread per 4 z-cells, NO atomics ----
// v4 (best measured: 62.7us gather in the round-12 pipeline): single fused
//   particle loop over all 9 (bi,bj) ranges -- one wave-max straggler tax
//   instead of nine. Range (s,e) pairs in LDS [range][tid] (bank = tid&31,
//   conflict-free, no barriers). 128-thread blocks (4096 granules).
//   Accumulation order per cell unchanged -> fp-identical results.
// Tested-and-rejected on this kernel: 2-wide unroll (r2: +VGPR, issue waste);
//   1-deep SW pipeline (r5: compiler re-folds); 64-thread blocks (r8:
//   occupancy drop); XCD-chunked swizzle (r8/r9: -7MB fetch but dense-region
//   concentration -> +imbalance); lane-pair split (r13: bookkeeping x2 and
//   +8MB offset fetch ate the straggler savings).
__global__ void __launch_bounds__(128)
grid_gather_kernel(const PRec* __restrict__ rec, const int* __restrict__ offset,
                   float4* __restrict__ grid, const float* __restrict__ gravity,
                   const float* __restrict__ attr_s, const float* __restrict__ attr_p) {
    __shared__ int rS[9*128];
    __shared__ int rE[9*128];
    int tid = threadIdx.x;
    int g4 = blockIdx.x*128 + tid;   // quad index (G3/4 total)
    int zq = g4 & 31;
    int gj = (g4 >> 5) & (NG-1);
    int gi = g4 >> 12;
    int zlo = zq*4;

    int bk0 = max(zlo-2, 0), bk1 = min(zlo+3, NG-3);

    // fetch all 9 column ranges (18 independent loads in flight) -> LDS table
    bool any = false;
    #pragma unroll
    for (int di = 0; di < 3; ++di) {
        int bi = gi - 2 + di;
        bool vi = (bi >= 0) && (bi <= NG-3);
        #pragma unroll
        for (int dj = 0; dj < 3; ++dj) {
            int bj = gj - 2 + dj;
            bool vj = vi && (bj >= 0) && (bj <= NG-3);
            int col = ((vj ? bi : 0)*NG + (vj ? bj : 0))*NG;
            int s = vj ? offset[col + bk0]     : 0;
            int e = vj ? offset[col + bk1 + 1] : 0;
            rS[(di*3+dj)*128 + tid] = s;
            rE[(di*3+dj)*128 + tid] = e;
            if (s < e) any = true;
        }
    }

    // quads with zero visits are never read by g2p (any cell g2p reads has a
    // member particle, and member particles lie in this quad's bucket window)
    if (!any) return;

    float ax[4], ay[4], az[4], mm[4];
    #pragma unroll
    for (int h = 0; h < 4; ++h) { ax[h]=0.f; ay[h]=0.f; az[h]=0.f; mm[h]=0.f; }

    float gif = (float)gi, gjf = (float)gj, z0f = (float)zlo;

    // fused stream over the 9 ranges (per-lane private advance)
    int ridx = 0;
    int p = rS[tid], e = rE[tid];
    while (p >= e) {
        if (++ridx >= 9) break;
        p = rS[ridx*128 + tid]; e = rE[ridx*128 + tid];
    }
    while (ridx < 9) {
        const float4* rp = (const float4*)&rec[p];
        float4 r0 = rp[0];
        float4 r1 = rp[1];
        float4 r2 = rp[2];
        float4 r3 = rp[3];

        // symmetric quadratic B-spline N(u), u = cell - A (fp-exact vs ref)
        float ux = gif - r0.x;
        float aux = fabsf(ux);
        float tx = 1.5f - aux;
        float nx = (aux < 0.5f) ? (0.75f - ux*ux) : (0.5f*tx*tx);
        float uy = gjf - r0.y;
        float auy = fabsf(uy);
        float ty = 1.5f - auy;
        float ny = (auy < 0.5f) ? (0.75f - uy*uy) : (0.5f*ty*ty);
        float wgt = nx*ny;                 // reference: x,y weights only

        float uz0 = z0f - r0.z;
        float dpx = ux*c_DX, dpy = uy*c_DX, dpz0 = uz0*c_DX;
        float cx = r3.y + r1.x*dpx + r1.y*dpy + r1.z*dpz0;
        float cy = r3.z + r1.w*dpx + r2.x*dpy + r2.y*dpz0;
        float cz = r3.w + r2.z*dpx + r2.w*dpy + r3.x*dpz0;
        float ix = r1.z*c_DX, iy = r2.y*c_DX, iz = r3.x*c_DX;

        #pragma unroll
        for (int h = 0; h < 4; ++h) {
            float uz = uz0 + (float)h;
            // membership mask: uz in (-1.5, 1.5]
            float w = (uz > -1.5f && uz <= 1.5f) ? wgt : 0.f;
            ax[h] += w*cx; ay[h] += w*cy; az[h] += w*cz; mm[h] += w*P_MASS;
            cx += ix; cy += iy; cz += iz;
        }

        ++p;
        while (p >= e) {
            if (++ridx >= 9) break;
            p = rS[ridx*128 + tid]; e = rE[ridx*128 + tid];
        }
    }

    float gx = DT*gravity[0]*30.0f, gy = DT*gravity[1]*30.0f, gz = DT*gravity[2]*30.0f;
    float apx = attr_p[0], apy = attr_p[1], apz = attr_p[2];
    float as  = attr_s[0] * DT * 100.0f;

    int gidx = (gi*NG + gj)*NG + zlo;
    #pragma unroll
    for (int h = 0; h < 4; ++h) {
        float m = mm[h];
        int gk = zlo + h;
        float gvx = 0.f, gvy = 0.f, gvz = 0.f;
        if (m > 0.f) {
            float inv = 1.0f/m;
            gvx = ax[h]*inv + gx; gvy = ay[h]*inv + gy; gvz = az[h]*inv + gz;
            float dx_ = apx - c_DX*(float)gi;
            float dy_ = apy - c_DX*(float)gj;
            float dz_ = apz - c_DX*(float)gk;
            float nrm = sqrtf(dx_*dx_ + dy_*dy_ + dz_*dz_);
            float sc = as / (0.01f + nrm);
            gvx += dx_*sc; gvy += dy_*sc; gvz += dz_*sc;
            if (gi < 3      && gvx < 0.f) gvx = 0.f;
            if (gi > NG-3   && gvx > 0.f) gvx = 0.f;
            if (gj < 3      && gvy < 0.f) gvy = 0.f;
            if (gj > NG-3   && gvy > 0.f) gvy = 0.f;
            // z unconstrained (matches reference)
        }
        grid[gidx + h] = make_float4(gvx, gvy, gvz, m);
    }
}

// ---------------- G2P (cell-sorted order, coalesced record reads) ----------------
__global__ void __launch_bounds__(256)
g2p_kernel(const PRec* __restrict__ rec, const float4* __restrict__ grid,
           float* __restrict__ out, int N) {
    int gid = blockIdx.x * 256 + threadIdx.x;
    if (gid >= N) return;

    float4 r0 = rec[gid].r0;
    float A0 = r0.x, A1 = r0.y, A2 = r0.z;
    int n = __float_as_int(r0.w);

    int bi, bj, bk; float fx0, fx1, fx2;
    base_from_A(A0, A1, A2, bi, bj, bk, fx0, fx1, fx2);

    float wx[3], wy[3];
    wx[0] = 0.5f*(1.5f-fx0)*(1.5f-fx0); wx[1] = 0.75f-(fx0-1.f)*(fx0-1.f); wx[2] = 0.5f*(fx0-0.5f)*(fx0-0.5f);
    wy[0] = 0.5f*(1.5f-fx1)*(1.5f-fx1); wy[1] = 0.75f-(fx1-1.f)*(fx1-1.f); wy[2] = 0.5f*(fx1-0.5f)*(fx1-0.5f);

    float nvx = 0.f, nvy = 0.f, nvz = 0.f;
    float nC[9];
    #pragma unroll
    for (int i = 0; i < 9; ++i) nC[i] = 0.f;

    #pragma unroll
    for (int i = 0; i < 3; ++i) {
        float dpx = (float)i - fx0;
        #pragma unroll
        for (int j = 0; j < 3; ++j) {
            float wgt = wx[i]*wy[j];
            float dpy = (float)j - fx1;
            int cell0 = ((bi+i)*NG + (bj+j))*NG + bk;
            #pragma unroll
            for (int k = 0; k < 3; ++k) {
                float dpz = (float)k - fx2;
                float4 gv = grid[cell0 + k];
                float wgx = wgt*gv.x, wgy = wgt*gv.y, wgz = wgt*gv.z;
                nvx += wgx; nvy += wgy; nvz += wgz;
                nC[0] += wgx*dpx; nC[1] += wgx*dpy; nC[2] += wgx*dpz;
                nC[3] += wgy*dpx; nC[4] += wgy*dpy; nC[5] += wgy*dpz;
                nC[6] += wgz*dpx; nC[7] += wgz*dpy; nC[8] += wgz*dpz;
            }
        }
    }

    float* po = out + (size_t)n*25;
    float px = A0*c_DX, py = A1*c_DX, pz = A2*c_DX;   // exact reconstruction
    po[0] = px + DT*nvx;
    po[1] = py + DT*nvy;
    po[2] = pz + DT*nvz;
    po[3] = nvx; po[4] = nvy; po[5] = nvz;
    float s4 = 4.0f*c_INV_DX;
    #pragma unroll
    for (int i = 0; i < 9; ++i) po[16+i] = s4*nC[i];
}

extern "C" void kernel_launch(void* const* d_in, const int* in_sizes, int n_in,
                              void* d_out, int out_size, void* d_ws, size_t ws_size,
                              hipStream_t stream) {
    const float* x        = (const float*)d_in[0];
    const float* v        = (const float*)d_in[1];
    const float* C        = (const float*)d_in[2];
    const float* F        = (const float*)d_in[3];
    const float* Jp       = (const float*)d_in[4];
    const float* gravity  = (const float*)d_in[5];
    const float* attr_s   = (const float*)d_in[6];
    const float* attr_p   = (const float*)d_in[7];
    const int*   material = (const int*)d_in[8];
    float* out = (float*)d_out;
    int N = in_sizes[0] / 3;

    // workspace (zeroed region first):
    //   [cell_count G3][state SCAN_NB][ticket pad] | [offset G3+1][rank N][grid][rec]
    char* ws = (char*)d_ws;
    size_t o = 0;
    int* cell_count = (int*)(ws + o);              o += (size_t)G3*sizeof(int);
    unsigned long long* state = (unsigned long long*)(ws + o);
                                                   o += (size_t)SCAN_NB*sizeof(unsigned long long);
    int* ticket     = (int*)(ws + o);              o += 128;   // padded
    size_t zero_bytes = o;
    int* offset     = (int*)(ws + o);              o += ((size_t)G3+1)*sizeof(int);
    int* rank       = (int*)(ws + o);              o += (size_t)N*sizeof(int);
    o = (o + 127) & ~(size_t)127;
    float4* grid    = (float4*)(ws + o);           o += (size_t)G3*sizeof(float4);
    PRec* rec       = (PRec*)(ws + o);             o += (size_t)N*sizeof(PRec);

    hipMemsetAsync(d_ws, 0, zero_bytes, stream);

    int pblocks = (N + 255) / 256;
    count_kernel<<<pblocks, 256, 0, stream>>>(x, cell_count, rank, N);
    scan_lookback_kernel<<<SCAN_NB, 256, 0, stream>>>(cell_count, offset,
                                                      state, ticket);
    pre_kernel<<<pblocks, 256, 0, stream>>>(x, v, C, F, Jp, material,
                                            offset, rank, rec, out, N);
    grid_gather_kernel<<<G3/512, 128, 0, stream>>>(rec, offset, grid,
                                                   gravity, attr_s, attr_p);
    g2p_kernel<<<pblocks, 256, 0, stream>>>(rec, grid, out, N);
}